// Round 8
// baseline (165.649 us; speedup 1.0000x reference)
//
#include <hip/hip_runtime.h>
#include <stdint.h>
#include <stddef.h>

// Problem constants (fixed by the reference).
constexpr int N_NODES = 10000;
constexpr int N_EDGES = 320000;
constexpr int DIM_IN  = 128;
constexpr int DIM_H   = 256;
constexpr int DIM_C   = 32;
constexpr int DIM_OUT = 64;
constexpr int DIM_QKV = DIM_C + DIM_C + DIM_H;  // 320 : [q|k|v]
constexpr int DIM_QK  = 2 * DIM_C;              // 64  : [q|k] compact fp32
constexpr int K_W1    = DIM_IN + DIM_H;         // 384 : [x | comm] composed W1 K-dim
constexpr float SCALE = 0.17677669529663687f;   // 1/sqrt(32)
constexpr int MAXD = 192;   // bucket capacity; Binomial(320k,1e-4) max ~66 (28 sigma margin)
constexpr float VSCALE = 64.0f;                 // fp8 v pre-scale (|v|max ~0.5 -> ~32 << 448)
constexpr int PAD2 = 72;    // 64-k LDS row stride (bf16): 144B rows, 16B-aligned (72=8*9)

#if __has_builtin(__builtin_amdgcn_cvt_pk_f32_fp8) && __has_builtin(__builtin_amdgcn_cvt_pk_fp8_f32)
#define V_FP8 1
#else
#define V_FP8 0   // fallback: bf16 v
#endif

// ---------------- workspace layout (4-byte words) ----------------
// h is NEVER materialized: W_in is pre-composed into W_eff (qkv) and W1big (w1w2).
constexpr size_t alignw(size_t w) { return (w + 15) & ~size_t(15); }
constexpr size_t OFF_DEG   = 0;
constexpr size_t OFF_COL   = alignw(OFF_DEG + N_NODES);                  // [N][MAXD] bucket
constexpr size_t OFF_QK    = alignw(OFF_COL + (size_t)N_NODES * MAXD);   // fp32 [N][64]
constexpr size_t OFF_VT    = alignw(OFF_QK + (size_t)N_NODES * DIM_QK);        // [N][256] fp8/bf16
constexpr size_t OFF_CMB   = alignw(OFF_VT + (size_t)N_NODES * DIM_H / 2);     // comm bf16 [N][256]
constexpr size_t OFF_WEFF  = alignw(OFF_CMB + (size_t)N_NODES * DIM_H / 2);    // [320][128] bf16
constexpr size_t OFF_W1BIG = alignw(OFF_WEFF + (size_t)DIM_QKV * DIM_IN / 2);  // [256][384] bf16
constexpr size_t OFF_W2T   = alignw(OFF_W1BIG + (size_t)DIM_H * K_W1 / 2);     // [64][256] bf16
constexpr size_t OFF_BEFF  = alignw(OFF_W2T + (size_t)DIM_OUT * DIM_H / 2);    // f32 [320]
constexpr size_t OFF_B1EFF = alignw(OFF_BEFF + DIM_QKV);                       // f32 [256]

typedef __attribute__((ext_vector_type(8))) short short8;
typedef __attribute__((ext_vector_type(4))) float floatx4;
typedef __attribute__((ext_vector_type(2))) float floatx2;

#define MFMA16 __builtin_amdgcn_mfma_f32_16x16x32_bf16

__device__ inline unsigned short f2bf(float f) {
    uint32_t u = __builtin_bit_cast(uint32_t, f);
    uint32_t r = (u + 0x7fffu + ((u >> 16) & 1u)) >> 16;   // RNE
    return (unsigned short)r;
}
__device__ inline float bf2f_lo(uint32_t u) { return __builtin_bit_cast(float, u << 16); }
__device__ inline float bf2f_hi(uint32_t u) { return __builtin_bit_cast(float, u & 0xffff0000u); }

// ---------------- prep: weight COMPOSITION + transposes + bias folds + deg zero -------
// W_effT[320][128]  = (W_in @ [Wq|Wk|Wv])^T          (qkv GEMM B, K=128)
// W1big [256][384]  = [(W_in @ W1_top)^T | W1_bot^T] (w1w2 phase-A B, K=384)
// b_eff[320] = b_in@Wqkv + bqkv ;  b1_eff[256] = b_in@W1_top + b1
// 320 threads/block, 330 blocks, branch by block range.
__global__ __launch_bounds__(320)
void prep(const float* __restrict__ W_in,
          const float* __restrict__ Wq, const float* __restrict__ Wk,
          const float* __restrict__ Wv,
          const float* __restrict__ bq, const float* __restrict__ bk,
          const float* __restrict__ bv, const float* __restrict__ b_in,
          const float* __restrict__ W1, const float* __restrict__ b1,
          const float* __restrict__ W2,
          int* __restrict__ deg,
          unsigned short* __restrict__ WeffT, unsigned short* __restrict__ W1big,
          unsigned short* __restrict__ W2T,
          float* __restrict__ b_eff, float* __restrict__ b1_eff)
{
    const int bid = blockIdx.x;
    const int tid = threadIdx.x;
    if (bid < 128) {
        // W_effT[n][k], k = bid, n = tid(0..319). W_in row broadcast, Wqkv read coalesced.
        const int k = bid, n = tid;
        float acc = 0.f;
        const float* wrow = W_in + (size_t)k * DIM_H;
        if (n < DIM_C) {
            for (int j = 0; j < DIM_H; ++j) acc += wrow[j] * Wq[j * DIM_C + n];
        } else if (n < DIM_QK) {
            for (int j = 0; j < DIM_H; ++j) acc += wrow[j] * Wk[j * DIM_C + (n - DIM_C)];
        } else {
            for (int j = 0; j < DIM_H; ++j) acc += wrow[j] * Wv[j * DIM_H + (n - DIM_QK)];
        }
        WeffT[n * DIM_IN + k] = f2bf(acc);
    } else if (bid < 256) {
        // W1big[n][k] (k<128 composed half), k = bid-128, n = tid<256.
        const int k = bid - 128, n = tid;
        if (n < DIM_H) {
            float acc = 0.f;
            const float* wrow = W_in + (size_t)k * DIM_H;
            for (int j = 0; j < DIM_H; ++j) acc += wrow[j] * W1[(size_t)j * DIM_H + n];
            W1big[n * K_W1 + k] = f2bf(acc);
        }
    } else if (bid < 288) {
        // W1big[n][128+jj] = W1_bot[jj][n]  (65,536 elems, coalesced read in n)
        for (int idx = (bid - 256) * 320 + tid; idx < DIM_H * DIM_H; idx += 32 * 320) {
            int jj = idx >> 8, n = idx & 255;
            W1big[n * K_W1 + DIM_IN + jj] = f2bf(W1[(size_t)(DIM_H + jj) * DIM_H + n]);
        }
    } else if (bid < 296) {
        // W2T[n][k] = W2[k][n]  (16,384 elems)
        for (int idx = (bid - 288) * 320 + tid; idx < DIM_H * DIM_OUT; idx += 8 * 320) {
            int k = idx >> 6, n = idx & 63;
            W2T[n * DIM_H + k] = f2bf(W2[(size_t)k * DIM_OUT + n]);
        }
    } else if (bid == 296) {
        // b_eff[n] = b_in @ Wqkv[:,n] + bqkv[n]
        const int n = tid;
        float acc;
        if (n < DIM_C) {
            acc = bq[n];
            for (int j = 0; j < DIM_H; ++j) acc += b_in[j] * Wq[j * DIM_C + n];
        } else if (n < DIM_QK) {
            acc = bk[n - DIM_C];
            for (int j = 0; j < DIM_H; ++j) acc += b_in[j] * Wk[j * DIM_C + (n - DIM_C)];
        } else {
            acc = bv[n - DIM_QK];
            for (int j = 0; j < DIM_H; ++j) acc += b_in[j] * Wv[j * DIM_H + (n - DIM_QK)];
        }
        b_eff[n] = acc;
    } else if (bid == 297) {
        // b1_eff[n] = b_in @ W1_top[:,n] + b1[n]
        const int n = tid;
        if (n < DIM_H) {
            float acc = b1[n];
            for (int j = 0; j < DIM_H; ++j) acc += b_in[j] * W1[(size_t)j * DIM_H + n];
            b1_eff[n] = acc;
        }
    } else {
        // deg zero: blocks 298..329 (32 x 320 = 10,240 >= 10,000)
        int i = (bid - 298) * 320 + tid;
        if (i < N_NODES) deg[i] = 0;
    }
}

// ---------------- gemm_qkv: qkv = x @ W_effT^T + b_eff  (K=128, 2 k-steps) ------------
// BM=32, N=320, 313 blocks, reg-prefetch. NO phase chain (h eliminated by composition).
// Tail: edge bucket-scatter (deg zeroed by prep). LDS 50.7 KB -> 3 blocks/CU.
__global__ __launch_bounds__(256)
void gemm_qkv(const float* __restrict__ x, const int* __restrict__ ei,
              const unsigned short* __restrict__ WeffT, const float* __restrict__ b_eff,
              int* __restrict__ deg, int* __restrict__ col,
              float* __restrict__ qk, unsigned short* __restrict__ v_tab)
{
    __shared__ alignas(16) char SMEM[50688];
    short* As = (short*)SMEM;                     // 32 x 72  =  4,608 B
    short* Bs = (short*)(SMEM + 4608);            // 320 x 72 = 46,080 B
    const int tid   = threadIdx.x;
    const int bid   = blockIdx.x;
    const int wave  = tid >> 6;
    const int lane  = tid & 63;
    const int quad  = lane >> 4;
    const int col16 = lane & 15;
    const int sr    = tid >> 3;          // staging row 0..31
    const int sc    = (tid & 7) * 8;     // staging k-chunk (8 bf16 = 16B), 0..56
    const int row0  = bid * 32;
    const int gr_s  = row0 + sr;

    // prologue: k0=0 tile loads
    float4 xa = {}, xb = {};
    if (gr_s < N_NODES) {
        const float4* xp = (const float4*)(x + (size_t)gr_s * DIM_IN + sc);
        xa = xp[0]; xb = xp[1];
    }
    short8 wreg[10];
    #pragma unroll
    for (int p = 0; p < 10; ++p)
        wreg[p] = *(const short8*)(WeffT + (size_t)(sr + p * 32) * DIM_IN + sc);

    floatx4 acc[2][5] = {};
    #pragma unroll
    for (int k0 = 0; k0 < DIM_IN; k0 += 64) {
        {   // ds_write staged x tile (inline f32->bf16)
            uint4 o;
            o.x = (uint32_t)f2bf(xa.x) | ((uint32_t)f2bf(xa.y) << 16);
            o.y = (uint32_t)f2bf(xa.z) | ((uint32_t)f2bf(xa.w) << 16);
            o.z = (uint32_t)f2bf(xb.x) | ((uint32_t)f2bf(xb.y) << 16);
            o.w = (uint32_t)f2bf(xb.z) | ((uint32_t)f2bf(xb.w) << 16);
            *(uint4*)(As + sr * PAD2 + sc) = o;
        }
        #pragma unroll
        for (int p = 0; p < 10; ++p)
            *(short8*)(Bs + (sr + p * 32) * PAD2 + sc) = wreg[p];
        if (k0 + 64 < DIM_IN) {   // prefetch second (last) k-step
            xa = {}; xb = {};
            if (gr_s < N_NODES) {
                const float4* xp = (const float4*)(x + (size_t)gr_s * DIM_IN + (k0 + 64) + sc);
                xa = xp[0]; xb = xp[1];
            }
            #pragma unroll
            for (int p = 0; p < 10; ++p)
                wreg[p] = *(const short8*)(WeffT + (size_t)(sr + p * 32) * DIM_IN + (k0 + 64) + sc);
        }
        __syncthreads();
        short8 af[2][2], bfr[5][2];
        #pragma unroll
        for (int m = 0; m < 2; ++m)
            #pragma unroll
            for (int kh = 0; kh < 2; ++kh)
                af[m][kh] = *(const short8*)(As + (m * 16 + col16) * PAD2 + kh * 32 + quad * 8);
        #pragma unroll
        for (int n = 0; n < 5; ++n)
            #pragma unroll
            for (int kh = 0; kh < 2; ++kh)
                bfr[n][kh] = *(const short8*)(Bs + (wave * 80 + n * 16 + col16) * PAD2 + kh * 32 + quad * 8);
        #pragma unroll
        for (int m = 0; m < 2; ++m)
            #pragma unroll
            for (int n = 0; n < 5; ++n)
                #pragma unroll
                for (int kh = 0; kh < 2; ++kh)
                    acc[m][n] = MFMA16(af[m][kh], bfr[n][kh], acc[m][n], 0, 0, 0);
        __syncthreads();
    }
    // epilogue: split -> qk fp32 [N][64], v fp8/bf16 [N][256]
    #pragma unroll
    for (int m = 0; m < 2; ++m)
        #pragma unroll
        for (int n = 0; n < 5; ++n) {
            int gc = wave * 80 + n * 16 + col16;
            float bia = b_eff[gc];
            #pragma unroll
            for (int r = 0; r < 4; ++r) {
                int gr = row0 + m * 16 + quad * 4 + r;
                if (gr >= N_NODES) continue;
                float v = acc[m][n][r] + bia;
                if (gc < DIM_QK) {
                    qk[(size_t)gr * DIM_QK + gc] = v;
                } else {
#if V_FP8
                    int pk = __builtin_amdgcn_cvt_pk_fp8_f32(v * VSCALE, 0.f, 0, false);
                    ((unsigned char*)v_tab)[(size_t)gr * DIM_H + (gc - DIM_QK)] =
                        (unsigned char)(pk & 0xff);
#else
                    v_tab[(size_t)gr * DIM_H + (gc - DIM_QK)] = f2bf(v);
#endif
                }
            }
        }

    // ---- tail (off critical path): edge bucket-scatter ----
    {
        const int stride = gridDim.x * 256;              // 80,128
        const int i0 = bid * 256 + tid;
        int s4[4], d4[4]; bool ok[4];
        #pragma unroll
        for (int t = 0; t < 4; ++t) {
            int e = i0 + t * stride;
            ok[t] = e < N_EDGES;
            s4[t] = ok[t] ? ei[e] : 0;
            d4[t] = ok[t] ? ei[N_EDGES + e] : 0;
        }
        #pragma unroll
        for (int t = 0; t < 4; ++t)
            if (ok[t]) {
                int slot = atomicAdd(&deg[s4[t]], 1);
                if (slot < MAXD) col[s4[t] * MAXD + slot] = d4[t];
            }
    }
}

// ---------------- fused per-row attention -> comm bf16 [N][256] -----------------------
// One wave per row, 4 rows per block (2500 blocks). R7-proven (4-wide LDS dedup).
__global__ __launch_bounds__(256)
void attn_row(const float* __restrict__ qk, const unsigned short* __restrict__ v_tab,
              const int* __restrict__ deg, const int* __restrict__ col,
              unsigned short* __restrict__ comm_bf) {
    __shared__ alignas(16) int dstS[4][MAXD];
    __shared__ float wS[4][MAXD];
    __shared__ float qS[4][DIM_C];
    const int wave = threadIdx.x >> 6;
    const int lane = threadIdx.x & 63;
    const int row = blockIdx.x * 4 + wave;   // grid is exactly N_NODES/4
    int d = deg[row];
    if (d > MAXD) d = MAXD;
    const int* crow = col + (size_t)row * MAXD;

    for (int p = lane; p < d; p += 64) dstS[wave][p] = crow[p];
    if (lane < DIM_C) qS[wave][lane] = qk[(size_t)row * DIM_QK + lane];
    __syncthreads();

    float mysum = 0.f;
    if (d <= 64) {
        int mydst = (lane < d) ? dstS[wave][lane] : -1;
        bool dup = false;
        {
            const int4* ds4 = (const int4*)(&dstS[wave][0]);
            const int lim = (lane < d) ? lane : 0;
            for (int j0 = 0; j0 < lim; j0 += 4) {
                int4 v = ds4[j0 >> 2];
                dup = dup || (v.x == mydst)
                   || (j0 + 1 < lim && v.y == mydst)
                   || (j0 + 2 < lim && v.z == mydst)
                   || (j0 + 3 < lim && v.w == mydst);
            }
        }
        float w = 0.f;
        if (lane < d && !dup) {
            const float4* kp = (const float4*)(qk + (size_t)mydst * DIM_QK + DIM_C);
            float s = 0.f;
            #pragma unroll
            for (int i = 0; i < DIM_C / 4; ++i) {
                float4 b = kp[i];
                s += qS[wave][4 * i + 0] * b.x + qS[wave][4 * i + 1] * b.y
                   + qS[wave][4 * i + 2] * b.z + qS[wave][4 * i + 3] * b.w;
            }
            w = expf(s * SCALE);
        }
        wS[wave][lane] = w;
        mysum = w;
    } else {
        for (int p = lane; p < d; p += 64) {
            int mydst = dstS[wave][p];
            bool dup = false;
            for (int j = 0; j < p; ++j) dup = dup || (dstS[wave][j] == mydst);
            float w = 0.f;
            if (!dup) {
                const float4* kp = (const float4*)(qk + (size_t)mydst * DIM_QK + DIM_C);
                float s = 0.f;
                #pragma unroll
                for (int i = 0; i < DIM_C / 4; ++i) {
                    float4 b = kp[i];
                    s += qS[wave][4 * i + 0] * b.x + qS[wave][4 * i + 1] * b.y
                       + qS[wave][4 * i + 2] * b.z + qS[wave][4 * i + 3] * b.w;
                }
                w = expf(s * SCALE);
            }
            wS[wave][p] = w;
            mysum += w;
        }
    }
    #pragma unroll
    for (int off = 32; off; off >>= 1) mysum += __shfl_down(mysum, off, 64);
    float total = __shfl(mysum, 0, 64);
#if V_FP8
    float inv = (d > 0 && total > 0.f) ? 1.0f / (total * VSCALE) : 0.f;
#else
    float inv = (d > 0 && total > 0.f) ? 1.0f / total : 0.f;
#endif
    __syncthreads();

    float4 acc = make_float4(0.f, 0.f, 0.f, 0.f);
#if V_FP8
    const uint32_t* vb = (const uint32_t*)v_tab;     // fp8 row = 64 dwords
#else
    const uint2* vb = (const uint2*)v_tab;           // bf16 row = 64 uint2
#endif
    for (int p0 = 0; p0 < d; p0 += 16) {
        int j[16]; float w[16];
        #pragma unroll
        for (int t = 0; t < 16; ++t) {
            int idx = p0 + t;
            bool in = idx < d;
            j[t] = in ? dstS[wave][idx] : 0;        // pad: row 0 (L2-hot), weight 0
            w[t] = in ? wS[wave][idx] : 0.f;
        }
#if V_FP8
        uint32_t r[16];
        #pragma unroll
        for (int t = 0; t < 16; ++t) r[t] = vb[(size_t)j[t] * 64 + lane];
        #pragma unroll
        for (int t = 0; t < 16; ++t) {
            floatx2 lo = __builtin_amdgcn_cvt_pk_f32_fp8(r[t], false);
            floatx2 hi = __builtin_amdgcn_cvt_pk_f32_fp8(r[t], true);
            acc.x += w[t] * lo.x; acc.y += w[t] * lo.y;
            acc.z += w[t] * hi.x; acc.w += w[t] * hi.y;
        }
#else
        uint2 r[16];
        #pragma unroll
        for (int t = 0; t < 16; ++t) r[t] = vb[(size_t)j[t] * 64 + lane];
        #pragma unroll
        for (int t = 0; t < 16; ++t) {
            acc.x += w[t] * bf2f_lo(r[t].x);
            acc.y += w[t] * bf2f_hi(r[t].x);
            acc.z += w[t] * bf2f_lo(r[t].y);
            acc.w += w[t] * bf2f_hi(r[t].y);
        }
#endif
    }
    acc.x *= inv; acc.y *= inv; acc.z *= inv; acc.w *= inv;
    uint2 o;
    o.x = (uint32_t)f2bf(acc.x) | ((uint32_t)f2bf(acc.y) << 16);
    o.y = (uint32_t)f2bf(acc.z) | ((uint32_t)f2bf(acc.w) << 16);
    *(uint2*)(comm_bf + (size_t)row * DIM_H + lane * 4) = o;
}

// ---------------- w1w2: out = relu(x@W1xeff + comm@W1bot + b1_eff) @ W2T + b2 ---------
// BM=32, K=384 (6 k-steps of 64: steps 0-1 A=x inline-cast, steps 2-5 A=comm bf16).
// B = W1big [256][384] contiguous. Reg-prefetch. LDS 41.5 KB -> 3 blocks/CU.
__global__ __launch_bounds__(256)
void gemm_w1w2(const float* __restrict__ x, const unsigned short* __restrict__ comm_bf,
               const unsigned short* __restrict__ W1big, const float* __restrict__ b1_eff,
               const unsigned short* __restrict__ W2T, const float* __restrict__ b2,
               float* __restrict__ out, int M)
{
    constexpr int TP = 260;   // Ts row stride (bf16)
    __shared__ short As[32 * PAD2];                //  4,608 B
    __shared__ short BsTs[256 * PAD2];             // 36,864 B: Bs; Ts (32*260*2=16,640) aliases
    short* Bs = BsTs;
    short* Ts = BsTs;
    const int tid   = threadIdx.x;
    const int wave  = tid >> 6;
    const int lane  = tid & 63;
    const int quad  = lane >> 4;
    const int col16 = lane & 15;
    const int row0  = blockIdx.x * 32;

    const int sr = tid >> 3;          // 0..31
    const int sc = (tid & 7) * 8;     // 16B k-chunk, 0..56
    const int gr_s = row0 + sr;

    // prologue: step-0 loads (A = x, f32)
    float4 xa = {}, xb = {};
    if (gr_s < M) {
        const float4* xp = (const float4*)(x + (size_t)gr_s * DIM_IN + sc);
        xa = xp[0]; xb = xp[1];
    }
    short8 acm = {};                  // A prefetch for comm steps (bf16)
    short8 breg[8];
    #pragma unroll
    for (int p = 0; p < 8; ++p)
        breg[p] = *(const short8*)(W1big + (size_t)(sr + p * 32) * K_W1 + sc);

    // ---- phase A: z = relu(A @ W1big^T + b1_eff), K = 384 ----
    floatx4 acc[2][4] = {};
    #pragma unroll
    for (int ks = 0; ks < 6; ++ks) {
        const int k0 = ks * 64;
        if (ks < 2) {   // A tile from x (inline cast)
            uint4 o;
            o.x = (uint32_t)f2bf(xa.x) | ((uint32_t)f2bf(xa.y) << 16);
            o.y = (uint32_t)f2bf(xa.z) | ((uint32_t)f2bf(xa.w) << 16);
            o.z = (uint32_t)f2bf(xb.x) | ((uint32_t)f2bf(xb.y) << 16);
            o.w = (uint32_t)f2bf(xb.z) | ((uint32_t)f2bf(xb.w) << 16);
            *(uint4*)(As + sr * PAD2 + sc) = o;
        } else {        // A tile from comm (bf16 direct)
            *(short8*)(As + sr * PAD2 + sc) = acm;
        }
        #pragma unroll
        for (int p = 0; p < 8; ++p)
            *(short8*)(Bs + (sr + p * 32) * PAD2 + sc) = breg[p];
        // prefetch next step (hidden under MFMA below)
        if (ks == 0) {
            xa = {}; xb = {};
            if (gr_s < M) {
                const float4* xp = (const float4*)(x + (size_t)gr_s * DIM_IN + 64 + sc);
                xa = xp[0]; xb = xp[1];
            }
        } else if (ks < 5) {
            acm = short8{};
            if (gr_s < M)
                acm = *(const short8*)(comm_bf + (size_t)gr_s * DIM_H + (k0 + 64 - DIM_IN) + sc);
        }
        if (ks < 5) {
            #pragma unroll
            for (int p = 0; p < 8; ++p)
                breg[p] = *(const short8*)(W1big + (size_t)(sr + p * 32) * K_W1 + (k0 + 64) + sc);
        }
        __syncthreads();
        short8 af[2][2], bfr[4][2];
        #pragma unroll
        for (int m = 0; m < 2; ++m)
            #pragma unroll
            for (int kh = 0; kh < 2; ++kh)
                af[m][kh] = *(const short8*)(As + (m * 16 + col16) * PAD2 + kh * 32 + quad * 8);
        #pragma unroll
        for (int n = 0; n < 4; ++n)
            #pragma unroll
            for (int kh = 0; kh < 2; ++kh)
                bfr[n][kh] = *(const short8*)(Bs + (wave * 64 + n * 16 + col16) * PAD2 + kh * 32 + quad * 8);
        #pragma unroll
        for (int m = 0; m < 2; ++m)
            #pragma unroll
            for (int n = 0; n < 4; ++n)
                #pragma unroll
                for (int kh = 0; kh < 2; ++kh)
                    acc[m][n] = MFMA16(af[m][kh], bfr[n][kh], acc[m][n], 0, 0, 0);
        __syncthreads();   // Bs reads done before next staging / Ts overwrite
    }

    // epilogue A: bias + relu -> bf16 z tile in Ts (aliases Bs; safe after final barrier)
    #pragma unroll
    for (int m = 0; m < 2; ++m)
        #pragma unroll
        for (int n = 0; n < 4; ++n) {
            int gc = wave * 64 + n * 16 + col16;
            float bia = b1_eff[gc];
            #pragma unroll
            for (int r = 0; r < 4; ++r) {
                int lr = m * 16 + quad * 4 + r;
                Ts[lr * TP + gc] = (short)f2bf(fmaxf(acc[m][n][r] + bia, 0.f));
            }
        }
    __syncthreads();

    // ---- phase B: out = z @ W2T^T + b2, K=256; wave owns cols [wave*16, wave*16+16) ----
    floatx4 acc2[2] = {};
    #pragma unroll
    for (int k0 = 0; k0 < DIM_H; k0 += 32) {
        short8 b = *(const short8*)(W2T + (size_t)(wave * 16 + col16) * DIM_H + k0 + quad * 8);
        #pragma unroll
        for (int m = 0; m < 2; ++m) {
            short8 a = *(const short8*)(Ts + (m * 16 + col16) * TP + k0 + quad * 8);
            acc2[m] = MFMA16(a, b, acc2[m], 0, 0, 0);
        }
    }
    #pragma unroll
    for (int m = 0; m < 2; ++m) {
        int gc = wave * 16 + col16;
        float bia = b2[gc];
        #pragma unroll
        for (int r = 0; r < 4; ++r) {
            int gr = row0 + m * 16 + quad * 4 + r;
            if (gr < M) out[(size_t)gr * DIM_OUT + gc] = acc2[m][r] + bia;
        }
    }
}

// ---------------- launcher: 4 dispatches ----------------
extern "C" void kernel_launch(void* const* d_in, const int* in_sizes, int n_in,
                              void* d_out, int out_size, void* d_ws, size_t ws_size,
                              hipStream_t stream) {
    (void)in_sizes; (void)n_in; (void)out_size; (void)ws_size;
    const float* x    = (const float*)d_in[0];
    const int*   ei   = (const int*)d_in[1];
    const float* W_in = (const float*)d_in[2];
    const float* b_in = (const float*)d_in[3];
    const float* Wq   = (const float*)d_in[4];
    const float* bq   = (const float*)d_in[5];
    const float* Wk   = (const float*)d_in[6];
    const float* bk   = (const float*)d_in[7];
    const float* Wv   = (const float*)d_in[8];
    const float* bv   = (const float*)d_in[9];
    const float* W1   = (const float*)d_in[10];
    const float* b1   = (const float*)d_in[11];
    const float* W2   = (const float*)d_in[12];
    const float* b2   = (const float*)d_in[13];
    float* out = (float*)d_out;

    uint32_t* ws      = (uint32_t*)d_ws;
    int*      deg     = (int*)(ws + OFF_DEG);
    int*      col     = (int*)(ws + OFF_COL);
    float*    qk      = (float*)(ws + OFF_QK);
    unsigned short* v_tab  = (unsigned short*)(ws + OFF_VT);
    unsigned short* comm_bf= (unsigned short*)(ws + OFF_CMB);
    unsigned short* WeffT  = (unsigned short*)(ws + OFF_WEFF);
    unsigned short* W1big  = (unsigned short*)(ws + OFF_W1BIG);
    unsigned short* W2T    = (unsigned short*)(ws + OFF_W2T);
    float*    b_eff   = (float*)(ws + OFF_BEFF);
    float*    b1_eff  = (float*)(ws + OFF_B1EFF);

    // 1) prep: weight composition (h eliminated algebraically) + transposes + deg zero
    prep<<<330, 320, 0, stream>>>(W_in, Wq, Wk, Wv, bq, bk, bv, b_in, W1, b1, W2,
                                  deg, WeffT, W1big, W2T, b_eff, b1_eff);
    // 2) qkv = x@W_eff + b_eff (K=128, single phase) + edge-scatter tail, 313 blocks
    gemm_qkv<<<(N_NODES + 31) / 32, 256, 0, stream>>>(
        x, ei, WeffT, b_eff, deg, col, qk, v_tab);
    // 3) fused sparse attention -> comm bf16 [N][256]
    attn_row<<<N_NODES / 4, 256, 0, stream>>>(qk, v_tab, deg, col, comm_bf);
    // 4) out = relu(x@W1xeff + comm@W1bot + b1_eff)@W2 + b2  (K=384), 313 blocks
    gemm_w1w2<<<(N_NODES + 31) / 32, 256, 0, stream>>>(
        x, comm_bf, W1big, b1_eff, W2T, b2, out, N_NODES);
}